// Round 10
// baseline (100.628 us; speedup 1.0000x reference)
//
#include <hip/hip_runtime.h>
#include <math.h>

// out_i = clamp(out_{i-1}; a_i, a_i+1), a_i = x_i * k.  Clamp functions
// p -> min(max(p,lo),hi) compose associatively -> parallel scan.
// Deterministic 2-dispatch scan (absmax 0.0 since R5).
//
// R10 = R9 with the compile fix: __builtin_nontemporal_* requires a native
// vector type, not HIP_vector_type -> use ext_vector_type(4) float.
// (1) NT stores for out + NT loads for K2's x re-read: harness's 256MiB
// 0xAA poison leaves L3 dirty; NT avoids forcing ~33MB writeback through
// the cache. (2) K2 issues all x loads BEFORE part (A)'s barrier.

#define TPB 256
#define WAVES (TPB / 64)
#define SEGS 4
#define FPL 8                        // contiguous floats per lane per segment
#define SEG_ELEMS (TPB * FPL)        // 2048
#define ELEMS (SEGS * SEG_ELEMS)     // 8192 -> 1024 blocks @ T=2^23

typedef float v4f __attribute__((ext_vector_type(4)));

__device__ __forceinline__ float clampf(float x, float lo, float hi) {
    return fminf(fmaxf(x, lo), hi);
}

// ---------------- K1: per-block composed clamp aggregate ----------------
__global__ __launch_bounds__(TPB) void k_agg(const v4f* __restrict__ x4,
                                             const float* __restrict__ kern,
                                             float2* __restrict__ agg) {
    __shared__ float wl[SEGS][WAVES], wh[SEGS][WAVES];
    const int t = threadIdx.x, lane = t & 63, w = t >> 6;
    const int b = blockIdx.x;
    const float k = kern[0];
    const size_t base4 = (size_t)b * (ELEMS / 4);

    // issue ALL loads first (independent), then reduce
    v4f v[SEGS][2];
#pragma unroll
    for (int s = 0; s < SEGS; ++s) {
        const size_t i4 = base4 + (size_t)s * (SEG_ELEMS / 4) + (size_t)t * 2;
        v[s][0] = x4[i4];
        v[s][1] = x4[i4 + 1];
    }

#pragma unroll
    for (int s = 0; s < SEGS; ++s) {
        float lo, hi, a;
        a = v[s][0].x * k; lo = a; hi = a + 1.0f;
        a = v[s][0].y * k; lo = clampf(lo, a, a + 1.0f); hi = clampf(hi, a, a + 1.0f);
        a = v[s][0].z * k; lo = clampf(lo, a, a + 1.0f); hi = clampf(hi, a, a + 1.0f);
        a = v[s][0].w * k; lo = clampf(lo, a, a + 1.0f); hi = clampf(hi, a, a + 1.0f);
        a = v[s][1].x * k; lo = clampf(lo, a, a + 1.0f); hi = clampf(hi, a, a + 1.0f);
        a = v[s][1].y * k; lo = clampf(lo, a, a + 1.0f); hi = clampf(hi, a, a + 1.0f);
        a = v[s][1].z * k; lo = clampf(lo, a, a + 1.0f); hi = clampf(hi, a, a + 1.0f);
        a = v[s][1].w * k; lo = clampf(lo, a, a + 1.0f); hi = clampf(hi, a, a + 1.0f);
        // ordered wave reduce: self (earlier) FIRST, lane+off (later) SECOND.
        // OOB shfl returns self; self-compose of a clamp pair is identity.
#pragma unroll
        for (int off = 1; off < 64; off <<= 1) {
            float plo = __shfl_down(lo, off);
            float phi_ = __shfl_down(hi, off);
            float nlo = clampf(lo, plo, phi_);
            float nhi = clampf(hi, plo, phi_);
            lo = nlo; hi = nhi;
        }
        if (lane == 0) { wl[s][w] = lo; wh[s][w] = hi; }
    }
    __syncthreads();
    if (t == 0) {
        float L = -INFINITY, H = INFINITY;
#pragma unroll
        for (int s = 0; s < SEGS; ++s)       // (s,w) lexicographic = element order
#pragma unroll
            for (int i = 0; i < WAVES; ++i) {
                L = clampf(L, wl[s][i], wh[s][i]);
                H = clampf(H, wl[s][i], wh[s][i]);
            }
        agg[b] = make_float2(L, H);
    }
}

// ------- K2: entry from agg prefix, per-segment scan, apply + write -------
__global__ __launch_bounds__(TPB) void k_apply(
    const v4f* __restrict__ x4,
    const float* __restrict__ kern,
    const float* __restrict__ state,
    const float2* __restrict__ agg,
    float* __restrict__ out,          // T outputs + 1 new_state
    int nblocks)
{
    __shared__ float rl[WAVES], rh[WAVES];
    __shared__ float wtl[SEGS][WAVES], wth[SEGS][WAVES];
    __shared__ float s_vb;

    const int t = threadIdx.x, lane = t & 63, w = t >> 6;
    const int b = blockIdx.x;
    const float k = kern[0];
    const size_t base4 = (size_t)b * (ELEMS / 4);

    // ---- (0) issue x loads FIRST so they fly during part (A)'s machinery ----
    v4f v[SEGS][2];
#pragma unroll
    for (int s = 0; s < SEGS; ++s) {
        const size_t i4 = base4 + (size_t)s * (SEG_ELEMS / 4) + (size_t)t * 2;
        v[s][0] = __builtin_nontemporal_load(&x4[i4]);       // last use of x
        v[s][1] = __builtin_nontemporal_load(&x4[i4 + 1]);
    }

    // ---- (A) block entry value: exclusive prefix over agg[0..b-1] ----
    {
        const int per = nblocks / TPB;   // 4
        float lo = -INFINITY, hi = INFINITY;
#pragma unroll
        for (int c = 0; c < per; ++c) {
            int j = t * per + c;
            if (j < b) {
                float2 ag = agg[j];
                lo = clampf(lo, ag.x, ag.y);
                hi = clampf(hi, ag.x, ag.y);
            }
        }
#pragma unroll
        for (int off = 1; off < 64; off <<= 1) {
            float plo = __shfl_down(lo, off);
            float phi_ = __shfl_down(hi, off);
            float nlo = clampf(lo, plo, phi_);
            float nhi = clampf(hi, plo, phi_);
            lo = nlo; hi = nhi;
        }
        if (lane == 0) { rl[w] = lo; rh[w] = hi; }
    }
    __syncthreads();
    if (t == 0) {
        float L = rl[0], H = rh[0];
#pragma unroll
        for (int i = 1; i < WAVES; ++i) {
            L = clampf(L, rl[i], rh[i]);
            H = clampf(H, rl[i], rh[i]);
        }
        s_vb = clampf(state[0], L, H);   // block entry VALUE
    }

    // ---- (B) per-segment local pair scan ----
    float a[SEGS][FPL];
    float eslo[SEGS], eshi[SEGS];
    float Slo[SEGS], Shi[SEGS];

#pragma unroll
    for (int s = 0; s < SEGS; ++s) {
        a[s][0] = v[s][0].x * k; a[s][1] = v[s][0].y * k;
        a[s][2] = v[s][0].z * k; a[s][3] = v[s][0].w * k;
        a[s][4] = v[s][1].x * k; a[s][5] = v[s][1].y * k;
        a[s][6] = v[s][1].z * k; a[s][7] = v[s][1].w * k;
        float lo = a[s][0], hi = a[s][0] + 1.0f;
#pragma unroll
        for (int c = 1; c < FPL; ++c) {
            lo = clampf(lo, a[s][c], a[s][c] + 1.0f);
            hi = clampf(hi, a[s][c], a[s][c] + 1.0f);
        }
        // wave inclusive scan on lane pairs (prefix FIRST, self SECOND)
#pragma unroll
        for (int off = 1; off < 64; off <<= 1) {
            float plo = __shfl_up(lo, off);
            float phi_ = __shfl_up(hi, off);
            if (lane >= off) {
                float nlo = clampf(plo, lo, hi);
                float nhi = clampf(phi_, lo, hi);
                lo = nlo; hi = nhi;
            }
        }
        float elo = __shfl_up(lo, 1), ehi = __shfl_up(hi, 1);
        if (lane == 0) { elo = -INFINITY; ehi = INFINITY; }
        eslo[s] = elo; eshi[s] = ehi;
        if (lane == 63) { wtl[s][w] = lo; wth[s][w] = hi; }
    }
    __syncthreads();

#pragma unroll
    for (int s = 0; s < SEGS; ++s) {
        float welo = -INFINITY, wehi = INFINITY;   // earlier waves in this segment
        for (int i = 0; i < w; ++i) {
            welo = clampf(welo, wtl[s][i], wth[s][i]);
            wehi = clampf(wehi, wtl[s][i], wth[s][i]);
        }
        float llo = eslo[s], lhi = eshi[s];
        eslo[s] = clampf(welo, llo, lhi);          // compose(waves-before, lanes-before)
        eshi[s] = clampf(wehi, llo, lhi);
        float stl = -INFINITY, sth = INFINITY;     // segment total
#pragma unroll
        for (int i = 0; i < WAVES; ++i) {
            stl = clampf(stl, wtl[s][i], wth[s][i]);
            sth = clampf(sth, wtl[s][i], wth[s][i]);
        }
        Slo[s] = stl; Shi[s] = sth;
    }

    // ---- (C) thread the value, apply, NT stores ----
    __syncthreads();                 // s_vb visible
    float p = s_vb;
    float wv = p;
#pragma unroll
    for (int s = 0; s < SEGS; ++s) {
        wv = clampf(p, eslo[s], eshi[s]);          // this thread's entry in segment
        v4f r0, r1;
        wv = clampf(wv, a[s][0], a[s][0] + 1.0f); r0.x = wv;
        wv = clampf(wv, a[s][1], a[s][1] + 1.0f); r0.y = wv;
        wv = clampf(wv, a[s][2], a[s][2] + 1.0f); r0.z = wv;
        wv = clampf(wv, a[s][3], a[s][3] + 1.0f); r0.w = wv;
        wv = clampf(wv, a[s][4], a[s][4] + 1.0f); r1.x = wv;
        wv = clampf(wv, a[s][5], a[s][5] + 1.0f); r1.y = wv;
        wv = clampf(wv, a[s][6], a[s][6] + 1.0f); r1.z = wv;
        wv = clampf(wv, a[s][7], a[s][7] + 1.0f); r1.w = wv;
        v4f* o = (v4f*)(out + (size_t)b * ELEMS + (size_t)s * SEG_ELEMS) + (size_t)t * 2;
        __builtin_nontemporal_store(r0, &o[0]);    // no-allocate: spare dirty L3
        __builtin_nontemporal_store(r1, &o[1]);
        p = clampf(p, Slo[s], Shi[s]);             // advance past segment
    }

    if (b == nblocks - 1 && t == TPB - 1)
        out[(size_t)nblocks * ELEMS] = wv;         // new_state = last output
}

extern "C" void kernel_launch(void* const* d_in, const int* in_sizes, int n_in,
                              void* d_out, int out_size, void* d_ws, size_t ws_size,
                              hipStream_t stream) {
    const v4f* x4      = (const v4f*)d_in[0];      // [1,T]
    const float* state = (const float*)d_in[1];    // [1,1]
    const float* kern  = (const float*)d_in[2];    // [1,1]
    float* out = (float*)d_out;                    // T outputs + 1 new_state

    const size_t T = (size_t)in_sizes[0];
    const int nblocks = (int)(T / ELEMS);          // 1024 for T=2^23
    float2* agg = (float2*)d_ws;                   // fully written by K1 before K2 reads

    k_agg<<<nblocks, TPB, 0, stream>>>(x4, kern, agg);
    k_apply<<<nblocks, TPB, 0, stream>>>(x4, kern, state, agg, out, nblocks);
}